// Round 9
// baseline (220.314 us; speedup 1.0000x reference)
//
#include <hip/hip_runtime.h>
#include <math.h>

#define B_ 8
#define L_ 1024
#define K_ 1024
#define D_ 128
#define S_ 16
#define DS_ (D_ * S_)
#define NIT_ 32          // full contraction, BK=32

typedef short bf16x8 __attribute__((ext_vector_type(8)));
typedef float f32x4 __attribute__((ext_vector_type(4)));
typedef __attribute__((address_space(1))) const unsigned int gu32;
typedef __attribute__((address_space(3))) unsigned int lu32;

__device__ inline unsigned short f2bf(float f) {
    unsigned int u = __float_as_uint(f);
    u = (u + 0x7fffu + ((u >> 16) & 1u)) >> 16;   // RNE
    return (unsigned short)u;
}
__device__ inline float bf2f(unsigned short h) {
    return __uint_as_float(((unsigned int)h) << 16);
}

// B operands (u', G) stored PRE-SWIZZLED in glds consumption order:
// idx = ((((b*32 + ct)*4 + q)*128 + n)*8 + i), c = ct*32 + q*8 + i.
__device__ inline size_t bswz(int b, int c, int n) {
    return ((((size_t)b * 32 + (c >> 5)) * 4 + ((c >> 3) & 3)) * 128 + n) * 8;
}

// ---------------------------------------------------------------------------
// Fused: params (blocks 0-7) + rownorm + BN + in-proj + swizzled bf16 hi/lo u.
// 16 rows/block, 512 blocks.
// ---------------------------------------------------------------------------
__global__ __launch_bounds__(256) void k_pre(
    const float* __restrict__ E, const float* __restrict__ x,
    const float* __restrict__ g, const float* __restrict__ beta,
    const float* __restrict__ mean, const float* __restrict__ var,
    const float* __restrict__ W_in, const float* __restrict__ b_in,
    const float* __restrict__ log_Delta, const float* __restrict__ Bp,
    const float* __restrict__ Cp, const float* __restrict__ log_A_real,
    const float* __restrict__ A_imag,
    float* __restrict__ rn_out, float* __restrict__ par,
    unsigned short* __restrict__ uswH, unsigned short* __restrict__ uswL) {
    __shared__ float xb[16][128];
    __shared__ float rsum[16];
    __shared__ float rnS[16];
    int bx = blockIdx.x;
    int row0 = bx * 16;
    int t = threadIdx.x;
    // --- params (double precision), spread over blocks 0-7 ---
    if (bx < 8) {
        int i = bx * 256 + t;                // i = d*S + s
        int d = i >> 4, s = i & 15;
        double delta = exp((double)log_Delta[d]);
        double Are = -exp((double)log_A_real[i]);
        double Aim = (double)A_imag[i];
        double mag = exp(-1e-3 + delta * Are);
        double ang = delta * Aim;
        int o = s * D_ + d;
        par[o]           = (float)(mag * cos(ang));
        par[DS_ + o]     = (float)(mag * sin(ang));
        par[2 * DS_ + o] = (float)(delta * (double)Bp[i] * (double)Cp[i]);
    }
    // --- row norms: 16 threads per row ---
    {
        int r = t >> 4, tt = t & 15;
        const float4* Ep = (const float4*)(E + (size_t)(row0 + r) * K_);
        float s = 0.f;
        #pragma unroll
        for (int i = 0; i < 16; ++i) {
            float4 v = Ep[tt + i * 16];
            s += v.x * v.x + v.y * v.y + v.z * v.z + v.w * v.w;
        }
        s += __shfl_xor(s, 8, 64);
        s += __shfl_xor(s, 4, 64);
        s += __shfl_xor(s, 2, 64);
        s += __shfl_xor(s, 1, 64);
        if (tt == 0) rsum[r] = s;
    }
    // --- stage BN(x) ---
    #pragma unroll
    for (int p = 0; p < 8; ++p) {
        int idx = t + p * 256;
        int dd = idx & 127, r = idx >> 7;
        float sc = g[dd] / sqrtf(var[dd] + 1e-5f);
        xb[r][dd] = (x[(size_t)(row0 + r) * D_ + dd] - mean[dd]) * sc + beta[dd];
    }
    __syncthreads();
    if (t < 16) {
        float rv = 1.0f / sqrtf(rsum[t]);
        rnS[t] = rv;
        rn_out[row0 + t] = rv;
    }
    __syncthreads();
    int j = t & 127, half = t >> 7;
    float acc1[8], acc2[8];
    #pragma unroll
    for (int r = 0; r < 8; ++r) { acc1[r] = 0.f; acc2[r] = 0.f; }
    #pragma unroll 4
    for (int dd = 0; dd < 128; ++dd) {
        float w1 = W_in[dd * 256 + j];
        float w2 = W_in[dd * 256 + 128 + j];
        #pragma unroll
        for (int r = 0; r < 8; ++r) {
            float xv = xb[half * 8 + r][dd];
            acc1[r] = fmaf(xv, w1, acc1[r]);
            acc2[r] = fmaf(xv, w2, acc2[r]);
        }
    }
    float b1 = b_in[j], b2 = b_in[128 + j];
    bf16x8 hv, lv;
    #pragma unroll
    for (int r = 0; r < 8; ++r) {
        int rr = half * 8 + r;
        float x1 = acc1[r] + b1;
        float z  = acc2[r] + b2;
        float sig = 1.0f / (1.0f + __expf(-z));
        float uv = rnS[rr] * x1 * z * sig;
        unsigned short h = f2bf(uv);
        hv[r] = (short)h;
        lv[r] = (short)f2bf(uv - bf2f(h));
    }
    int b = row0 >> 10;
    int l0 = (row0 & 1023) + half * 8;
    size_t off = bswz(b, l0, j);
    *(bf16x8*)&uswH[off] = hv;
    *(bf16x8*)&uswL[off] = lv;
}

// ---- shared staging helper ------------------------------------------------
__device__ inline void cvt4_write(const float* v, unsigned short* sh,
                                  unsigned short* sl, int offShorts) {
    unsigned short hs[4], ls[4];
    #pragma unroll
    for (int i = 0; i < 4; ++i) {
        hs[i] = f2bf(v[i]);
        ls[i] = f2bf(v[i] - bf2f(hs[i]));
    }
    *(uint2*)&sh[offShorts] = (uint2){(unsigned)hs[0] | ((unsigned)hs[1] << 16),
                                      (unsigned)hs[2] | ((unsigned)hs[3] << 16)};
    *(uint2*)&sl[offShorts] = (uint2){(unsigned)ls[0] | ((unsigned)ls[1] << 16),
                                      (unsigned)ls[2] | ((unsigned)ls[3] << 16)};
}

// ---------------------------------------------------------------------------
// k_g1: GEMM1 (QTX = E^T @ u', KS=1, tile 32k x 128d) + fused gepi epilogue
// -> writes Gsw (swizzled bf16 hi/lo). Grid = 32 ktiles * 8 b = 256 blocks.
// NOTE: BbH/BbL are batch-offset; src0 must NOT include b again (R7/R8 bug:
// double batch offset made b>0 read garbage -> y ~ noise).
// ---------------------------------------------------------------------------
__global__ __launch_bounds__(256) void k_g1(
    const float* __restrict__ E,
    const unsigned short* __restrict__ BH, const unsigned short* __restrict__ BL,
    const float* __restrict__ EigVals, const float* __restrict__ par,
    unsigned short* __restrict__ GswH, unsigned short* __restrict__ GswL) {
    __shared__ unsigned short sAh[2][1280], sAl[2][1280];
    __shared__ unsigned short sBh[2][4128], sBl[2][4128];
    __shared__ float evS[32];
    __shared__ float Gs[32][132];
    int bx = blockIdx.x;
    int b = bx & 7;
    int m0 = (bx >> 3) * 32;                 // k-tile base
    const float* Ab = E + (size_t)b * (1024 * 1024);
    const unsigned short* BbH = BH + (size_t)b * 131072;
    const unsigned short* BbL = BL + (size_t)b * 131072;
    int t = threadIdx.x;
    int wave = t >> 6, lane = t & 63;
    int fr = lane & 15, q = lane >> 4;
    int wn = wave * 32;
    int am = t & 31, acg = t >> 5;           // A-stage: m=am, c=acg*4+i
    int ap = ((acg >> 1) + (am >> 3)) & 3;   // rotated 8-short group
    int aoff = am * 40 + ap * 8 + (acg & 1) * 4;
    if (t < 32) evS[t] = 1.0f - EigVals[b * 1024 + m0 + t];
    f32x4 acc[2][2];
    #pragma unroll
    for (int i = 0; i < 2; ++i)
        #pragma unroll
        for (int jj = 0; jj < 2; ++jj) acc[i][jj] = (f32x4){0.f, 0.f, 0.f, 0.f};
    float va[2][4];
    // ---- prologue: stage it=0 into buf0; prefetch A for it=1 ----
    {
        #pragma unroll
        for (int i = 0; i < 4; ++i)
            va[0][i] = Ab[(size_t)(acg * 4 + i) * 1024 + m0 + am];
        size_t src0 = 0;                     // ct = 0 (b lives in BbH/BbL only)
        #pragma unroll
        for (int jj = 0; jj < 4; ++jj) {
            int s = wave + jj * 4;
            int qq = s & 3, nh = (s >> 2) & 1, hl = s >> 3;
            const unsigned short* src =
                (hl ? BbL : BbH) + src0 + ((size_t)qq * 128 + nh * 64 + lane) * 8;
            unsigned short* dst = (hl ? sBl[0] : sBh[0]) + qq * 1032 + nh * 512;
            __builtin_amdgcn_global_load_lds((gu32*)src, (lu32*)dst, 16, 0, 0);
        }
        cvt4_write(va[0], sAh[0], sAl[0], aoff);
        #pragma unroll
        for (int i = 0; i < 4; ++i)
            va[1][i] = Ab[(size_t)(32 + acg * 4 + i) * 1024 + m0 + am];
    }
    __syncthreads();
    for (int it = 0; it < NIT_; ++it) {
        int cur = it & 1, nxt = cur ^ 1;
        if (it + 1 < NIT_) {
            size_t src0 = (size_t)(it + 1) * 4096;   // ct = it+1
            #pragma unroll
            for (int jj = 0; jj < 4; ++jj) {
                int s = wave + jj * 4;
                int qq = s & 3, nh = (s >> 2) & 1, hl = s >> 3;
                const unsigned short* src =
                    (hl ? BbL : BbH) + src0 + ((size_t)qq * 128 + nh * 64 + lane) * 8;
                unsigned short* dst = (hl ? sBl[nxt] : sBh[nxt]) + qq * 1032 + nh * 512;
                __builtin_amdgcn_global_load_lds((gu32*)src, (lu32*)dst, 16, 0, 0);
            }
            cvt4_write(va[(it + 1) & 1], sAh[nxt], sAl[nxt], aoff);
        }
        if (it + 2 < NIT_) {
            #pragma unroll
            for (int i = 0; i < 4; ++i)
                va[it & 1][i] = Ab[(size_t)((it + 2) * 32 + acg * 4 + i) * 1024 + m0 + am];
        }
        bf16x8 ah[2], al[2], bh[2], bl[2];
        #pragma unroll
        for (int mt = 0; mt < 2; ++mt) {
            int r = mt * 16 + fr;
            int p = (q + (r >> 3)) & 3;
            int off = r * 40 + p * 8;
            ah[mt] = *(const bf16x8*)&sAh[cur][off];
            al[mt] = *(const bf16x8*)&sAl[cur][off];
        }
        #pragma unroll
        for (int nt = 0; nt < 2; ++nt) {
            int off = q * 1032 + (wn + nt * 16 + fr) * 8;
            bh[nt] = *(const bf16x8*)&sBh[cur][off];
            bl[nt] = *(const bf16x8*)&sBl[cur][off];
        }
        #pragma unroll
        for (int mt = 0; mt < 2; ++mt)
            #pragma unroll
            for (int nt = 0; nt < 2; ++nt) {
                acc[mt][nt] = __builtin_amdgcn_mfma_f32_16x16x32_bf16(
                    ah[mt], bh[nt], acc[mt][nt], 0, 0, 0);
                acc[mt][nt] = __builtin_amdgcn_mfma_f32_16x16x32_bf16(
                    ah[mt], bl[nt], acc[mt][nt], 0, 0, 0);
                acc[mt][nt] = __builtin_amdgcn_mfma_f32_16x16x32_bf16(
                    al[mt], bh[nt], acc[mt][nt], 0, 0, 0);
            }
        __syncthreads();
    }
    // ---- epilogue phase 1: dump raw QTX into Gs ----
    #pragma unroll
    for (int mt = 0; mt < 2; ++mt)
        #pragma unroll
        for (int nt = 0; nt < 2; ++nt) {
            int col = wn + nt * 16 + fr;
            #pragma unroll
            for (int r = 0; r < 4; ++r)
                Gs[mt * 16 + q * 4 + r][col] = acc[mt][nt][r];
        }
    __syncthreads();
    // ---- phase 2: Gs *= w(ev,col); par hoisted into regs from global ----
    {
        int col = t & 127, rowg = t >> 7;
        float arr[S_], aii[S_], ccc[S_];
        #pragma unroll
        for (int ss = 0; ss < S_; ++ss) {
            arr[ss] = par[ss * D_ + col];
            aii[ss] = par[DS_ + ss * D_ + col];
            ccc[ss] = par[2 * DS_ + ss * D_ + col];
        }
        #pragma unroll
        for (int i = 0; i < 16; ++i) {
            int row = rowg * 16 + i;
            float ev = evS[row];
            float w = 0.f;
            #pragma unroll
            for (int ss = 0; ss < S_; ++ss) {
                float a = ev * arr[ss], bi = ev * aii[ss];
                float oma = 1.0f - a;            // exact (Sterbenz), a in [0.5,1]
                float b2 = bi * bi;
                float num = fmaf(a, oma, -b2);
                float den = fmaf(oma, oma, b2);  // no cancellation
                float rr = __builtin_amdgcn_rcpf(den);
                rr = rr * (2.0f - den * rr);
                w = fmaf(ccc[ss], num * rr, w);
            }
            Gs[row][col] *= w;
        }
    }
    __syncthreads();
    // ---- phase 3: swizzled bf16 hi/lo write-out ----
    int ct = m0 >> 5;
    #pragma unroll
    for (int jj = 0; jj < 2; ++jj) {
        int tau = t + jj * 256;
        int d = tau & 127, kg = tau >> 7;    // kg in [0,4)
        bf16x8 hv, lv;
        #pragma unroll
        for (int i = 0; i < 8; ++i) {
            float v = Gs[kg * 8 + i][d];
            unsigned short h = f2bf(v);
            hv[i] = (short)h;
            lv[i] = (short)f2bf(v - bf2f(h));
        }
        size_t off = (((size_t)(b * 32 + ct) * 4 + kg) * 128 + d) * 8;
        *(bf16x8*)&GswH[off] = hv;
        *(bf16x8*)&GswL[off] = lv;
    }
}

// ---------------------------------------------------------------------------
// k_g2: GEMM2 (yssm = E @ G, KS=1, tile 32l x 128d) + fused rn/silu/out-proj
// epilogue -> writes y. Grid = 32 ltiles * 8 b = 256 blocks.
// Same src0 fix as k_g1.
// ---------------------------------------------------------------------------
__global__ __launch_bounds__(256) void k_g2(
    const float* __restrict__ E,
    const unsigned short* __restrict__ BH, const unsigned short* __restrict__ BL,
    const float* __restrict__ rn, const float* __restrict__ W_out,
    const float* __restrict__ b_out, float* __restrict__ y) {
    __shared__ unsigned short sAh[2][1280], sAl[2][1280];
    __shared__ unsigned short sBh[2][4128], sBl[2][4128];
    __shared__ float Ys[32][132];
    __shared__ float rnS[32];
    int bx = blockIdx.x;
    int b = bx & 7;
    int m0 = (bx >> 3) * 32;                 // l-tile base
    const float* Ab = E + (size_t)b * (1024 * 1024);
    const unsigned short* BbH = BH + (size_t)b * 131072;
    const unsigned short* BbL = BL + (size_t)b * 131072;
    int t = threadIdx.x;
    int wave = t >> 6, lane = t & 63;
    int fr = lane & 15, q = lane >> 4;
    int wn = wave * 32;
    int am = t >> 3, acg = t & 7;            // A-stage: m=am, c=acg*4+i (float4)
    int ap = ((acg >> 1) + (am >> 3)) & 3;
    int aoff = am * 40 + ap * 8 + (acg & 1) * 4;
    if (t < 32) rnS[t] = rn[b * 1024 + m0 + t];
    f32x4 acc[2][2];
    #pragma unroll
    for (int i = 0; i < 2; ++i)
        #pragma unroll
        for (int jj = 0; jj < 2; ++jj) acc[i][jj] = (f32x4){0.f, 0.f, 0.f, 0.f};
    float va[2][4];
    {
        *(float4*)&va[0][0] = *(const float4*)&Ab[(size_t)(m0 + am) * 1024 + acg * 4];
        size_t src0 = 0;                     // ct = 0
        #pragma unroll
        for (int jj = 0; jj < 4; ++jj) {
            int s = wave + jj * 4;
            int qq = s & 3, nh = (s >> 2) & 1, hl = s >> 3;
            const unsigned short* src =
                (hl ? BbL : BbH) + src0 + ((size_t)qq * 128 + nh * 64 + lane) * 8;
            unsigned short* dst = (hl ? sBl[0] : sBh[0]) + qq * 1032 + nh * 512;
            __builtin_amdgcn_global_load_lds((gu32*)src, (lu32*)dst, 16, 0, 0);
        }
        cvt4_write(va[0], sAh[0], sAl[0], aoff);
        *(float4*)&va[1][0] = *(const float4*)&Ab[(size_t)(m0 + am) * 1024 + 32 + acg * 4];
    }
    __syncthreads();
    for (int it = 0; it < NIT_; ++it) {
        int cur = it & 1, nxt = cur ^ 1;
        if (it + 1 < NIT_) {
            size_t src0 = (size_t)(it + 1) * 4096;   // ct = it+1
            #pragma unroll
            for (int jj = 0; jj < 4; ++jj) {
                int s = wave + jj * 4;
                int qq = s & 3, nh = (s >> 2) & 1, hl = s >> 3;
                const unsigned short* src =
                    (hl ? BbL : BbH) + src0 + ((size_t)qq * 128 + nh * 64 + lane) * 8;
                unsigned short* dst = (hl ? sBl[nxt] : sBh[nxt]) + qq * 1032 + nh * 512;
                __builtin_amdgcn_global_load_lds((gu32*)src, (lu32*)dst, 16, 0, 0);
            }
            cvt4_write(va[(it + 1) & 1], sAh[nxt], sAl[nxt], aoff);
        }
        if (it + 2 < NIT_) {
            *(float4*)&va[it & 1][0] =
                *(const float4*)&Ab[(size_t)(m0 + am) * 1024 + (it + 2) * 32 + acg * 4];
        }
        bf16x8 ah[2], al[2], bh[2], bl[2];
        #pragma unroll
        for (int mt = 0; mt < 2; ++mt) {
            int r = mt * 16 + fr;
            int p = (q + (r >> 3)) & 3;
            int off = r * 40 + p * 8;
            ah[mt] = *(const bf16x8*)&sAh[cur][off];
            al[mt] = *(const bf16x8*)&sAl[cur][off];
        }
        #pragma unroll
        for (int nt = 0; nt < 2; ++nt) {
            int off = q * 1032 + (wn + nt * 16 + fr) * 8;
            bh[nt] = *(const bf16x8*)&sBh[cur][off];
            bl[nt] = *(const bf16x8*)&sBl[cur][off];
        }
        #pragma unroll
        for (int mt = 0; mt < 2; ++mt)
            #pragma unroll
            for (int nt = 0; nt < 2; ++nt) {
                acc[mt][nt] = __builtin_amdgcn_mfma_f32_16x16x32_bf16(
                    ah[mt], bh[nt], acc[mt][nt], 0, 0, 0);
                acc[mt][nt] = __builtin_amdgcn_mfma_f32_16x16x32_bf16(
                    ah[mt], bl[nt], acc[mt][nt], 0, 0, 0);
                acc[mt][nt] = __builtin_amdgcn_mfma_f32_16x16x32_bf16(
                    al[mt], bh[nt], acc[mt][nt], 0, 0, 0);
            }
        __syncthreads();
    }
    // ---- fused epilogue: Ys = silu(yssm*rn); y = Ys @ W_out + b_out ----
    #pragma unroll
    for (int mt = 0; mt < 2; ++mt)
        #pragma unroll
        for (int nt = 0; nt < 2; ++nt) {
            int col = wn + nt * 16 + fr;
            #pragma unroll
            for (int r = 0; r < 4; ++r) {
                int row = mt * 16 + q * 4 + r;
                float v = acc[mt][nt][r] * rnS[row];
                float sig = 1.0f / (1.0f + __expf(-v));
                Ys[row][col] = v * sig;
            }
        }
    __syncthreads();
    int j = t & 127, h = t >> 7;             // h in {0,1}: 16 rows each
    float a2[16];
    #pragma unroll
    for (int r = 0; r < 16; ++r) a2[r] = 0.f;
    for (int dd = 0; dd < 128; dd += 4) {
        float w0 = W_out[(dd + 0) * 128 + j];
        float w1 = W_out[(dd + 1) * 128 + j];
        float w2 = W_out[(dd + 2) * 128 + j];
        float w3 = W_out[(dd + 3) * 128 + j];
        #pragma unroll
        for (int r = 0; r < 16; ++r) {
            float4 yv = *(float4*)&Ys[h * 16 + r][dd];
            a2[r] = fmaf(yv.x, w0, a2[r]);
            a2[r] = fmaf(yv.y, w1, a2[r]);
            a2[r] = fmaf(yv.z, w2, a2[r]);
            a2[r] = fmaf(yv.w, w3, a2[r]);
        }
    }
    float bo = b_out[j];
    #pragma unroll
    for (int r = 0; r < 16; ++r)
        y[((size_t)b * 1024 + m0 + h * 16 + r) * 128 + j] = a2[r] + bo;
}

// ---------------------------------------------------------------------------
extern "C" void kernel_launch(void* const* d_in, const int* in_sizes, int n_in,
                              void* d_out, int out_size, void* d_ws, size_t ws_size,
                              hipStream_t stream) {
    const float* x          = (const float*)d_in[0];
    const float* EigVecs    = (const float*)d_in[2];
    const float* EigVals    = (const float*)d_in[3];
    const float* bn_gamma   = (const float*)d_in[4];
    const float* bn_beta    = (const float*)d_in[5];
    const float* bn_mean    = (const float*)d_in[6];
    const float* bn_var     = (const float*)d_in[7];
    const float* W_in       = (const float*)d_in[8];
    const float* b_in       = (const float*)d_in[9];
    const float* log_Delta  = (const float*)d_in[10];
    const float* Bp         = (const float*)d_in[11];
    const float* Cp         = (const float*)d_in[12];
    const float* log_A_real = (const float*)d_in[13];
    const float* A_imag     = (const float*)d_in[14];
    const float* W_out      = (const float*)d_in[15];
    const float* b_out      = (const float*)d_in[16];

    float* y = (float*)d_out;
    char* w = (char*)d_ws;
    float* rn            = (float*)(w);                       // 32 KB
    float* par           = (float*)(w + 32768);               // 24 KB
    unsigned short* uswH = (unsigned short*)(w + 65536);      // 2 MB each
    unsigned short* uswL = (unsigned short*)(w + 65536 + (1u << 21));
    unsigned short* GswH = (unsigned short*)(w + 65536 + 2 * (1u << 21));
    unsigned short* GswL = (unsigned short*)(w + 65536 + 3 * (1u << 21));

    k_pre<<<dim3(B_ * L_ / 16), dim3(256), 0, stream>>>(
        EigVecs, x, bn_gamma, bn_beta, bn_mean, bn_var, W_in, b_in,
        log_Delta, Bp, Cp, log_A_real, A_imag, rn, par, uswH, uswL);
    k_g1<<<dim3(256), dim3(256), 0, stream>>>(
        EigVecs, uswH, uswL, EigVals, par, GswH, GswL);
    k_g2<<<dim3(256), dim3(256), 0, stream>>>(
        EigVecs, GswH, GswL, rn, W_out, b_out, y);
}

// Round 10
// 182.406 us; speedup vs baseline: 1.2078x; 1.2078x over previous
//
#include <hip/hip_runtime.h>
#include <math.h>

#define B_ 8
#define L_ 1024
#define K_ 1024
#define D_ 128
#define S_ 16
#define DS_ (D_ * S_)
#define NIT_ 32          // full contraction, BK=32

typedef short bf16x8 __attribute__((ext_vector_type(8)));
typedef float f32x4 __attribute__((ext_vector_type(4)));
typedef __attribute__((address_space(1))) const unsigned int gu32;
typedef __attribute__((address_space(3))) unsigned int lu32;

__device__ inline unsigned short f2bf(float f) {
    unsigned int u = __float_as_uint(f);
    u = (u + 0x7fffu + ((u >> 16) & 1u)) >> 16;   // RNE
    return (unsigned short)u;
}
__device__ inline float bf2f(unsigned short h) {
    return __uint_as_float(((unsigned int)h) << 16);
}

// B operands (u', G) stored PRE-SWIZZLED in glds consumption order:
// idx = ((((b*32 + ct)*4 + q)*128 + n)*8 + i), c = ct*32 + q*8 + i.
__device__ inline size_t bswz(int b, int c, int n) {
    return ((((size_t)b * 32 + (c >> 5)) * 4 + ((c >> 3) & 3)) * 128 + n) * 8;
}

// ---------------------------------------------------------------------------
// Fused: params (blocks 0-7) + rownorm + BN + in-proj + swizzled bf16 hi/lo u.
// 16 rows/block, 512 blocks.
// ---------------------------------------------------------------------------
__global__ __launch_bounds__(256) void k_pre(
    const float* __restrict__ E, const float* __restrict__ x,
    const float* __restrict__ g, const float* __restrict__ beta,
    const float* __restrict__ mean, const float* __restrict__ var,
    const float* __restrict__ W_in, const float* __restrict__ b_in,
    const float* __restrict__ log_Delta, const float* __restrict__ Bp,
    const float* __restrict__ Cp, const float* __restrict__ log_A_real,
    const float* __restrict__ A_imag,
    float* __restrict__ rn_out, float* __restrict__ par,
    unsigned short* __restrict__ uswH, unsigned short* __restrict__ uswL) {
    __shared__ float xb[16][128];
    __shared__ float rsum[16];
    __shared__ float rnS[16];
    int bx = blockIdx.x;
    int row0 = bx * 16;
    int t = threadIdx.x;
    // --- params (double precision), spread over blocks 0-7 ---
    if (bx < 8) {
        int i = bx * 256 + t;                // i = d*S + s
        int d = i >> 4, s = i & 15;
        double delta = exp((double)log_Delta[d]);
        double Are = -exp((double)log_A_real[i]);
        double Aim = (double)A_imag[i];
        double mag = exp(-1e-3 + delta * Are);
        double ang = delta * Aim;
        int o = s * D_ + d;
        par[o]           = (float)(mag * cos(ang));
        par[DS_ + o]     = (float)(mag * sin(ang));
        par[2 * DS_ + o] = (float)(delta * (double)Bp[i] * (double)Cp[i]);
    }
    // --- row norms: 16 threads per row ---
    {
        int r = t >> 4, tt = t & 15;
        const float4* Ep = (const float4*)(E + (size_t)(row0 + r) * K_);
        float s = 0.f;
        #pragma unroll
        for (int i = 0; i < 16; ++i) {
            float4 v = Ep[tt + i * 16];
            s += v.x * v.x + v.y * v.y + v.z * v.z + v.w * v.w;
        }
        s += __shfl_xor(s, 8, 64);
        s += __shfl_xor(s, 4, 64);
        s += __shfl_xor(s, 2, 64);
        s += __shfl_xor(s, 1, 64);
        if (tt == 0) rsum[r] = s;
    }
    // --- stage BN(x) ---
    #pragma unroll
    for (int p = 0; p < 8; ++p) {
        int idx = t + p * 256;
        int dd = idx & 127, r = idx >> 7;
        float sc = g[dd] / sqrtf(var[dd] + 1e-5f);
        xb[r][dd] = (x[(size_t)(row0 + r) * D_ + dd] - mean[dd]) * sc + beta[dd];
    }
    __syncthreads();
    if (t < 16) {
        float rv = 1.0f / sqrtf(rsum[t]);
        rnS[t] = rv;
        rn_out[row0 + t] = rv;
    }
    __syncthreads();
    int j = t & 127, half = t >> 7;
    float acc1[8], acc2[8];
    #pragma unroll
    for (int r = 0; r < 8; ++r) { acc1[r] = 0.f; acc2[r] = 0.f; }
    #pragma unroll 4
    for (int dd = 0; dd < 128; ++dd) {
        float w1 = W_in[dd * 256 + j];
        float w2 = W_in[dd * 256 + 128 + j];
        #pragma unroll
        for (int r = 0; r < 8; ++r) {
            float xv = xb[half * 8 + r][dd];
            acc1[r] = fmaf(xv, w1, acc1[r]);
            acc2[r] = fmaf(xv, w2, acc2[r]);
        }
    }
    float b1 = b_in[j], b2 = b_in[128 + j];
    bf16x8 hv, lv;
    #pragma unroll
    for (int r = 0; r < 8; ++r) {
        int rr = half * 8 + r;
        float x1 = acc1[r] + b1;
        float z  = acc2[r] + b2;
        float sig = 1.0f / (1.0f + __expf(-z));
        float uv = rnS[rr] * x1 * z * sig;
        unsigned short h = f2bf(uv);
        hv[r] = (short)h;
        lv[r] = (short)f2bf(uv - bf2f(h));
    }
    int b = row0 >> 10;
    int l0 = (row0 & 1023) + half * 8;
    size_t off = bswz(b, l0, j);
    *(bf16x8*)&uswH[off] = hv;
    *(bf16x8*)&uswL[off] = lv;
}

// ---------------------------------------------------------------------------
// k_g1: GEMM1 (QTX = E^T @ u', tile 16k x 128d, full K) + fused gepi epilogue
// -> writes Gsw. Grid = 64 ktiles * 8 b = 512 blocks -> 2 blocks/CU.
// Single-buffered m97-style loop (load, barrier, MFMA, barrier): the two
// co-resident blocks cover each other's vmcnt drains (R9 at 1 block/CU had
// nothing to overlap -> 5000 cyc/iter of stall).
// LDS = 27.6 KB. acc = 8 VGPRs.
// ---------------------------------------------------------------------------
__global__ __launch_bounds__(256) void k_g1(
    const float* __restrict__ E,
    const unsigned short* __restrict__ BH, const unsigned short* __restrict__ BL,
    const float* __restrict__ EigVals, const float* __restrict__ par,
    unsigned short* __restrict__ GswH, unsigned short* __restrict__ GswL) {
    __shared__ unsigned short sAh[16 * 40], sAl[16 * 40];
    __shared__ unsigned short sBh[4128], sBl[4128];
    __shared__ float evS[16];
    __shared__ float Gs[16][132];
    int bx = blockIdx.x;
    int b = bx & 7;
    int m0 = (bx >> 3) * 16;                 // k-tile base (64 tiles)
    const float* Ab = E + (size_t)b * (1024 * 1024);
    const unsigned short* BbH = BH + (size_t)b * 131072;
    const unsigned short* BbL = BL + (size_t)b * 131072;
    int t = threadIdx.x;
    int wave = t >> 6, lane = t & 63;
    int fr = lane & 15, q = lane >> 4;
    int wn = wave * 32;
    // A staging: thread t loads E[cb+j2 .. +1][m0+am] (coalesced over am)
    int am = t & 15, j2 = (t >> 4) * 2;
    int ap = ((j2 >> 3) + (am >> 3)) & 3;
    int aoff = am * 40 + ap * 8 + (j2 & 7);
    if (t < 16) evS[t] = 1.0f - EigVals[b * 1024 + m0 + t];
    f32x4 acc[2];
    acc[0] = (f32x4){0.f, 0.f, 0.f, 0.f};
    acc[1] = (f32x4){0.f, 0.f, 0.f, 0.f};

    for (int it = 0; it < NIT_; ++it) {
        int cb = it * 32;
        // ---- A loads (2 dwords, coalesced 64B over am) ----
        float v0 = Ab[(size_t)(cb + j2) * 1024 + m0 + am];
        float v1 = Ab[(size_t)(cb + j2 + 1) * 1024 + m0 + am];
        // ---- B glds (16 x 1KB, coalesced; wave-uniform dst) ----
        size_t src0 = (size_t)it * 4096;
        #pragma unroll
        for (int jj = 0; jj < 4; ++jj) {
            int s = wave + jj * 4;
            int qq = s & 3, nh = (s >> 2) & 1, hl = s >> 3;
            const unsigned short* src =
                (hl ? BbL : BbH) + src0 + ((size_t)qq * 128 + nh * 64 + lane) * 8;
            unsigned short* dst = (hl ? sBl : sBh) + qq * 1032 + nh * 512;
            __builtin_amdgcn_global_load_lds((gu32*)src, (lu32*)dst, 16, 0, 0);
        }
        // ---- convert + ds_write A (one dword each) ----
        {
            unsigned short h0 = f2bf(v0), h1 = f2bf(v1);
            unsigned short l0 = f2bf(v0 - bf2f(h0)), l1 = f2bf(v1 - bf2f(h1));
            *(unsigned int*)&sAh[aoff] = (unsigned)h0 | ((unsigned)h1 << 16);
            *(unsigned int*)&sAl[aoff] = (unsigned)l0 | ((unsigned)l1 << 16);
        }
        __syncthreads();
        // ---- fragments + 6 MFMA ----
        bf16x8 ah, al, bh[2], bl[2];
        {
            int p = (q + (fr >> 3)) & 3;
            int off = fr * 40 + p * 8;
            ah = *(const bf16x8*)&sAh[off];
            al = *(const bf16x8*)&sAl[off];
        }
        #pragma unroll
        for (int nt = 0; nt < 2; ++nt) {
            int off = q * 1032 + (wn + nt * 16 + fr) * 8;
            bh[nt] = *(const bf16x8*)&sBh[off];
            bl[nt] = *(const bf16x8*)&sBl[off];
        }
        #pragma unroll
        for (int nt = 0; nt < 2; ++nt) {
            acc[nt] = __builtin_amdgcn_mfma_f32_16x16x32_bf16(ah, bh[nt], acc[nt], 0, 0, 0);
            acc[nt] = __builtin_amdgcn_mfma_f32_16x16x32_bf16(ah, bl[nt], acc[nt], 0, 0, 0);
            acc[nt] = __builtin_amdgcn_mfma_f32_16x16x32_bf16(al, bh[nt], acc[nt], 0, 0, 0);
        }
        __syncthreads();
    }
    // ---- epilogue phase 1: dump raw QTX into Gs (C/D: col=fr, row=q*4+r) ----
    #pragma unroll
    for (int nt = 0; nt < 2; ++nt) {
        int col = wn + nt * 16 + fr;
        #pragma unroll
        for (int r = 0; r < 4; ++r)
            Gs[q * 4 + r][col] = acc[nt][r];
    }
    __syncthreads();
    // ---- phase 2: Gs *= w(ev,col); par from global (L2-hot 24 KB) ----
    {
        int col = t & 127, rowg = t >> 7;    // 8 rows each
        float arr[S_], aii[S_], ccc[S_];
        #pragma unroll
        for (int ss = 0; ss < S_; ++ss) {
            arr[ss] = par[ss * D_ + col];
            aii[ss] = par[DS_ + ss * D_ + col];
            ccc[ss] = par[2 * DS_ + ss * D_ + col];
        }
        #pragma unroll
        for (int i = 0; i < 8; ++i) {
            int row = rowg * 8 + i;
            float ev = evS[row];
            float w = 0.f;
            #pragma unroll
            for (int ss = 0; ss < S_; ++ss) {
                float a = ev * arr[ss], bi = ev * aii[ss];
                float oma = 1.0f - a;            // exact (Sterbenz), a in [0.5,1]
                float b2 = bi * bi;
                float num = fmaf(a, oma, -b2);
                float den = fmaf(oma, oma, b2);  // no cancellation
                float rr = __builtin_amdgcn_rcpf(den);
                rr = rr * (2.0f - den * rr);
                w = fmaf(ccc[ss], num * rr, w);
            }
            Gs[row][col] *= w;
        }
    }
    __syncthreads();
    // ---- phase 3: swizzled bf16 hi/lo write-out (16 rows = half a ct) ----
    {
        int d = t & 127, kg = t >> 7;        // kg in {0,1}: rows kg*8..+8
        bf16x8 hv, lv;
        #pragma unroll
        for (int i = 0; i < 8; ++i) {
            float v = Gs[kg * 8 + i][d];
            unsigned short h = f2bf(v);
            hv[i] = (short)h;
            lv[i] = (short)f2bf(v - bf2f(h));
        }
        int ct = m0 >> 5;
        int qsel = ((m0 >> 3) & 2) + kg;     // quarter within the ct
        size_t off = (((size_t)(b * 32 + ct) * 4 + qsel) * 128 + d) * 8;
        *(bf16x8*)&GswH[off] = hv;
        *(bf16x8*)&GswL[off] = lv;
    }
}

// ---------------------------------------------------------------------------
// k_g2: GEMM2 (yssm = E @ G, tile 16l x 128d, full K) + fused rn/silu/out-proj
// epilogue -> writes y. Grid = 64 ltiles * 8 b = 512 blocks -> 2 blocks/CU.
// ---------------------------------------------------------------------------
__global__ __launch_bounds__(256) void k_g2(
    const float* __restrict__ E,
    const unsigned short* __restrict__ BH, const unsigned short* __restrict__ BL,
    const float* __restrict__ rn, const float* __restrict__ W_out,
    const float* __restrict__ b_out, float* __restrict__ y) {
    __shared__ unsigned short sAh[16 * 40], sAl[16 * 40];
    __shared__ unsigned short sBh[4128], sBl[4128];
    __shared__ float Ys[16][132];
    __shared__ float rnS[16];
    int bx = blockIdx.x;
    int b = bx & 7;
    int m0 = (bx >> 3) * 16;                 // l-tile base
    const float* Ab = E + (size_t)b * (1024 * 1024);
    const unsigned short* BbH = BH + (size_t)b * 131072;
    const unsigned short* BbL = BL + (size_t)b * 131072;
    int t = threadIdx.x;
    int wave = t >> 6, lane = t & 63;
    int fr = lane & 15, q = lane >> 4;
    int wn = wave * 32;
    // A staging: thread t loads E[m0+am][cb+j2 .. +1] (coalesced over j2)
    int am = t >> 4, j2 = (t & 15) * 2;
    int ap = ((j2 >> 3) + (am >> 3)) & 3;
    int aoff = am * 40 + ap * 8 + (j2 & 7);
    if (t < 16) rnS[t] = rn[b * 1024 + m0 + t];
    f32x4 acc[2];
    acc[0] = (f32x4){0.f, 0.f, 0.f, 0.f};
    acc[1] = (f32x4){0.f, 0.f, 0.f, 0.f};

    for (int it = 0; it < NIT_; ++it) {
        int cb = it * 32;
        // ---- A load (float2, coalesced 128B over j2) ----
        float2 va = *(const float2*)&Ab[(size_t)(m0 + am) * 1024 + cb + j2];
        // ---- B glds ----
        size_t src0 = (size_t)it * 4096;
        #pragma unroll
        for (int jj = 0; jj < 4; ++jj) {
            int s = wave + jj * 4;
            int qq = s & 3, nh = (s >> 2) & 1, hl = s >> 3;
            const unsigned short* src =
                (hl ? BbL : BbH) + src0 + ((size_t)qq * 128 + nh * 64 + lane) * 8;
            unsigned short* dst = (hl ? sBl : sBh) + qq * 1032 + nh * 512;
            __builtin_amdgcn_global_load_lds((gu32*)src, (lu32*)dst, 16, 0, 0);
        }
        // ---- convert + ds_write A ----
        {
            unsigned short h0 = f2bf(va.x), h1 = f2bf(va.y);
            unsigned short l0 = f2bf(va.x - bf2f(h0)), l1 = f2bf(va.y - bf2f(h1));
            *(unsigned int*)&sAh[aoff] = (unsigned)h0 | ((unsigned)h1 << 16);
            *(unsigned int*)&sAl[aoff] = (unsigned)l0 | ((unsigned)l1 << 16);
        }
        __syncthreads();
        // ---- fragments + 6 MFMA ----
        bf16x8 ah, al, bh[2], bl[2];
        {
            int p = (q + (fr >> 3)) & 3;
            int off = fr * 40 + p * 8;
            ah = *(const bf16x8*)&sAh[off];
            al = *(const bf16x8*)&sAl[off];
        }
        #pragma unroll
        for (int nt = 0; nt < 2; ++nt) {
            int off = q * 1032 + (wn + nt * 16 + fr) * 8;
            bh[nt] = *(const bf16x8*)&sBh[off];
            bl[nt] = *(const bf16x8*)&sBl[off];
        }
        #pragma unroll
        for (int nt = 0; nt < 2; ++nt) {
            acc[nt] = __builtin_amdgcn_mfma_f32_16x16x32_bf16(ah, bh[nt], acc[nt], 0, 0, 0);
            acc[nt] = __builtin_amdgcn_mfma_f32_16x16x32_bf16(ah, bl[nt], acc[nt], 0, 0, 0);
            acc[nt] = __builtin_amdgcn_mfma_f32_16x16x32_bf16(al, bh[nt], acc[nt], 0, 0, 0);
        }
        __syncthreads();
    }
    // ---- fused epilogue: Ys = silu(yssm*rn) ----
    #pragma unroll
    for (int nt = 0; nt < 2; ++nt) {
        int col = wn + nt * 16 + fr;
        #pragma unroll
        for (int r = 0; r < 4; ++r) {
            int row = q * 4 + r;
            float v = acc[nt][r] * rnS[row];
            float sig = 1.0f / (1.0f + __expf(-v));
            Ys[row][col] = v * sig;
        }
    }
    __syncthreads();
    // ---- out-proj: y = Ys @ W_out + b_out ----
    int j = t & 127, h = t >> 7;             // h in {0,1}: 8 rows each
    float a2[8];
    #pragma unroll
    for (int r = 0; r < 8; ++r) a2[r] = 0.f;
    for (int dd = 0; dd < 128; dd += 4) {
        float w0 = W_out[(dd + 0) * 128 + j];
        float w1 = W_out[(dd + 1) * 128 + j];
        float w2 = W_out[(dd + 2) * 128 + j];
        float w3 = W_out[(dd + 3) * 128 + j];
        #pragma unroll
        for (int r = 0; r < 8; ++r) {
            float4 yv = *(float4*)&Ys[h * 8 + r][dd];
            a2[r] = fmaf(yv.x, w0, a2[r]);
            a2[r] = fmaf(yv.y, w1, a2[r]);
            a2[r] = fmaf(yv.z, w2, a2[r]);
            a2[r] = fmaf(yv.w, w3, a2[r]);
        }
    }
    float bo = b_out[j];
    #pragma unroll
    for (int r = 0; r < 8; ++r)
        y[((size_t)b * 1024 + m0 + h * 8 + r) * 128 + j] = a2[r] + bo;
}

// ---------------------------------------------------------------------------
extern "C" void kernel_launch(void* const* d_in, const int* in_sizes, int n_in,
                              void* d_out, int out_size, void* d_ws, size_t ws_size,
                              hipStream_t stream) {
    const float* x          = (const float*)d_in[0];
    const float* EigVecs    = (const float*)d_in[2];
    const float* EigVals    = (const float*)d_in[3];
    const float* bn_gamma   = (const float*)d_in[4];
    const float* bn_beta    = (const float*)d_in[5];
    const float* bn_mean    = (const float*)d_in[6];
    const float* bn_var     = (const float*)d_in[7];
    const float* W_in       = (const float*)d_in[8];
    const float* b_in       = (const float*)d_in[9];
    const float* log_Delta  = (const float*)d_in[10];
    const float* Bp         = (const float*)d_in[11];
    const float* Cp         = (const float*)d_in[12];
    const float* log_A_real = (const float*)d_in[13];
    const float* A_imag     = (const float*)d_in[14];
    const float* W_out      = (const float*)d_in[15];
    const float* b_out      = (const float*)d_in[16];

    float* y = (float*)d_out;
    char* w = (char*)d_ws;
    float* rn            = (float*)(w);                       // 32 KB
    float* par           = (float*)(w + 32768);               // 24 KB
    unsigned short* uswH = (unsigned short*)(w + 65536);      // 2 MB each
    unsigned short* uswL = (unsigned short*)(w + 65536 + (1u << 21));
    unsigned short* GswH = (unsigned short*)(w + 65536 + 2 * (1u << 21));
    unsigned short* GswL = (unsigned short*)(w + 65536 + 3 * (1u << 21));

    k_pre<<<dim3(B_ * L_ / 16), dim3(256), 0, stream>>>(
        EigVecs, x, bn_gamma, bn_beta, bn_mean, bn_var, W_in, b_in,
        log_Delta, Bp, Cp, log_A_real, A_imag, rn, par, uswH, uswL);
    k_g1<<<dim3(512), dim3(256), 0, stream>>>(
        EigVecs, uswH, uswL, EigVals, par, GswH, GswL);
    k_g2<<<dim3(512), dim3(256), 0, stream>>>(
        EigVecs, GswH, GswL, rn, W_out, b_out, y);
}

// Round 11
// 173.975 us; speedup vs baseline: 1.2664x; 1.0485x over previous
//
#include <hip/hip_runtime.h>
#include <math.h>

#define B_ 8
#define L_ 1024
#define K_ 1024
#define D_ 128
#define S_ 16
#define DS_ (D_ * S_)
#define NIT_ 16          // full contraction, BK=64

typedef short bf16x8 __attribute__((ext_vector_type(8)));
typedef float f32x4 __attribute__((ext_vector_type(4)));
typedef __attribute__((address_space(1))) const unsigned int gu32;
typedef __attribute__((address_space(3))) unsigned int lu32;

__device__ inline unsigned short f2bf(float f) {
    unsigned int u = __float_as_uint(f);
    u = (u + 0x7fffu + ((u >> 16) & 1u)) >> 16;   // RNE
    return (unsigned short)u;
}
__device__ inline float bf2f(unsigned short h) {
    return __uint_as_float(((unsigned int)h) << 16);
}

// B operands (u', G) stored PRE-SWIZZLED in glds consumption order:
// idx = ((((b*32 + ct)*4 + q)*128 + n)*8 + i), c = ct*32 + q*8 + i.
__device__ inline size_t bswz(int b, int c, int n) {
    return ((((size_t)b * 32 + (c >> 5)) * 4 + ((c >> 3) & 3)) * 128 + n) * 8;
}

// ---------------------------------------------------------------------------
// Fused: params (blocks 0-7) + rownorm + BN + in-proj + swizzled bf16 hi/lo u.
// 16 rows/block, 512 blocks.
// ---------------------------------------------------------------------------
__global__ __launch_bounds__(256) void k_pre(
    const float* __restrict__ E, const float* __restrict__ x,
    const float* __restrict__ g, const float* __restrict__ beta,
    const float* __restrict__ mean, const float* __restrict__ var,
    const float* __restrict__ W_in, const float* __restrict__ b_in,
    const float* __restrict__ log_Delta, const float* __restrict__ Bp,
    const float* __restrict__ Cp, const float* __restrict__ log_A_real,
    const float* __restrict__ A_imag,
    float* __restrict__ rn_out, float* __restrict__ par,
    unsigned short* __restrict__ uswH, unsigned short* __restrict__ uswL) {
    __shared__ float xb[16][128];
    __shared__ float rsum[16];
    __shared__ float rnS[16];
    int bx = blockIdx.x;
    int row0 = bx * 16;
    int t = threadIdx.x;
    // --- params (double precision), spread over blocks 0-7 ---
    if (bx < 8) {
        int i = bx * 256 + t;                // i = d*S + s
        int d = i >> 4, s = i & 15;
        double delta = exp((double)log_Delta[d]);
        double Are = -exp((double)log_A_real[i]);
        double Aim = (double)A_imag[i];
        double mag = exp(-1e-3 + delta * Are);
        double ang = delta * Aim;
        int o = s * D_ + d;
        par[o]           = (float)(mag * cos(ang));
        par[DS_ + o]     = (float)(mag * sin(ang));
        par[2 * DS_ + o] = (float)(delta * (double)Bp[i] * (double)Cp[i]);
    }
    // --- row norms: 16 threads per row ---
    {
        int r = t >> 4, tt = t & 15;
        const float4* Ep = (const float4*)(E + (size_t)(row0 + r) * K_);
        float s = 0.f;
        #pragma unroll
        for (int i = 0; i < 16; ++i) {
            float4 v = Ep[tt + i * 16];
            s += v.x * v.x + v.y * v.y + v.z * v.z + v.w * v.w;
        }
        s += __shfl_xor(s, 8, 64);
        s += __shfl_xor(s, 4, 64);
        s += __shfl_xor(s, 2, 64);
        s += __shfl_xor(s, 1, 64);
        if (tt == 0) rsum[r] = s;
    }
    // --- stage BN(x) ---
    #pragma unroll
    for (int p = 0; p < 8; ++p) {
        int idx = t + p * 256;
        int dd = idx & 127, r = idx >> 7;
        float sc = g[dd] / sqrtf(var[dd] + 1e-5f);
        xb[r][dd] = (x[(size_t)(row0 + r) * D_ + dd] - mean[dd]) * sc + beta[dd];
    }
    __syncthreads();
    if (t < 16) {
        float rv = 1.0f / sqrtf(rsum[t]);
        rnS[t] = rv;
        rn_out[row0 + t] = rv;
    }
    __syncthreads();
    int j = t & 127, half = t >> 7;
    float acc1[8], acc2[8];
    #pragma unroll
    for (int r = 0; r < 8; ++r) { acc1[r] = 0.f; acc2[r] = 0.f; }
    #pragma unroll 4
    for (int dd = 0; dd < 128; ++dd) {
        float w1 = W_in[dd * 256 + j];
        float w2 = W_in[dd * 256 + 128 + j];
        #pragma unroll
        for (int r = 0; r < 8; ++r) {
            float xv = xb[half * 8 + r][dd];
            acc1[r] = fmaf(xv, w1, acc1[r]);
            acc2[r] = fmaf(xv, w2, acc2[r]);
        }
    }
    float b1 = b_in[j], b2 = b_in[128 + j];
    bf16x8 hv, lv;
    #pragma unroll
    for (int r = 0; r < 8; ++r) {
        int rr = half * 8 + r;
        float x1 = acc1[r] + b1;
        float z  = acc2[r] + b2;
        float sig = 1.0f / (1.0f + __expf(-z));
        float uv = rnS[rr] * x1 * z * sig;
        unsigned short h = f2bf(uv);
        hv[r] = (short)h;
        lv[r] = (short)f2bf(uv - bf2f(h));
    }
    int b = row0 >> 10;
    int l0 = (row0 & 1023) + half * 8;
    size_t off = bswz(b, l0, j);
    *(bf16x8*)&uswH[off] = hv;
    *(bf16x8*)&uswL[off] = lv;
}

// ---------------------------------------------------------------------------
// k_g1: GEMM1 (QTX = E^T @ u', tile 16k x 128d, BK=64, full K) + gepi epilogue
// -> writes Gsw. Grid = 64 ktiles * 8 b = 512 blocks -> 2 blocks/CU.
// BK=64 halves the number of barrier drains vs R10 (the dominant per-iter
// cost: ~2850 cyc/iter measured). LDS ~52 KB, still 2 blocks/CU.
// A LDS: 2 chunks (c in [ks*32,+32)), each [16m][40] shorts w/ rotation.
// B LDS: 2 ct-sections of the proven q-stride-1032 layout.
// ---------------------------------------------------------------------------
__global__ __launch_bounds__(256) void k_g1(
    const float* __restrict__ E,
    const unsigned short* __restrict__ BH, const unsigned short* __restrict__ BL,
    const float* __restrict__ EigVals, const float* __restrict__ par,
    unsigned short* __restrict__ GswH, unsigned short* __restrict__ GswL) {
    __shared__ unsigned short sAh[2][640], sAl[2][640];
    __shared__ unsigned short sBh[2][4128], sBl[2][4128];
    __shared__ float evS[16];
    __shared__ float Gs[16][132];
    int bx = blockIdx.x;
    int b = bx & 7;
    int m0 = (bx >> 3) * 16;                 // k-tile base (64 tiles)
    const float* Ab = E + (size_t)b * (1024 * 1024);
    const unsigned short* BbH = BH + (size_t)b * 131072;
    const unsigned short* BbL = BL + (size_t)b * 131072;
    int t = threadIdx.x;
    int wave = t >> 6, lane = t & 63;
    int fr = lane & 15, q = lane >> 4;
    int wn = wave * 32;
    // A staging: thread t handles m=am, c-pairs {2jj,2jj+1} (chunk0) and +32 (chunk1)
    int am = t & 15, jj = t >> 4;            // jj in [0,16)
    int ag = jj >> 2;                        // 8-short group within chunk
    int arot = (ag + (am >> 3)) & 3;
    int aoff = am * 40 + arot * 8 + ((2 * jj) & 7);
    if (t < 16) evS[t] = 1.0f - EigVals[b * 1024 + m0 + t];
    f32x4 acc[2];
    acc[0] = (f32x4){0.f, 0.f, 0.f, 0.f};
    acc[1] = (f32x4){0.f, 0.f, 0.f, 0.f};

    for (int it = 0; it < NIT_; ++it) {
        int cb = it * 64;
        // ---- A loads: 4 dwords (coalesced 64B over am) ----
        float v0 = Ab[(size_t)(cb + 2 * jj) * 1024 + m0 + am];
        float v1 = Ab[(size_t)(cb + 2 * jj + 1) * 1024 + m0 + am];
        float v2 = Ab[(size_t)(cb + 32 + 2 * jj) * 1024 + m0 + am];
        float v3 = Ab[(size_t)(cb + 32 + 2 * jj + 1) * 1024 + m0 + am];
        // ---- B glds: 2 ct-sections, 8 per wave, coalesced 1KB each ----
        #pragma unroll
        for (int j2 = 0; j2 < 8; ++j2) {
            int s = wave + j2 * 4;           // [0,32)
            int cts = s >> 4, s2 = s & 15;
            int qq = s2 & 3, nh = (s2 >> 2) & 1, hl = s2 >> 3;
            size_t src0 = (size_t)(it * 2 + cts) * 4096;
            const unsigned short* src =
                (hl ? BbL : BbH) + src0 + ((size_t)qq * 128 + nh * 64 + lane) * 8;
            unsigned short* dst = (hl ? sBl[cts] : sBh[cts]) + qq * 1032 + nh * 512;
            __builtin_amdgcn_global_load_lds((gu32*)src, (lu32*)dst, 16, 0, 0);
        }
        // ---- convert + ds_write A (one dword per chunk) ----
        {
            unsigned short h0 = f2bf(v0), h1 = f2bf(v1);
            unsigned short l0 = f2bf(v0 - bf2f(h0)), l1 = f2bf(v1 - bf2f(h1));
            *(unsigned int*)&sAh[0][aoff] = (unsigned)h0 | ((unsigned)h1 << 16);
            *(unsigned int*)&sAl[0][aoff] = (unsigned)l0 | ((unsigned)l1 << 16);
            unsigned short h2 = f2bf(v2), h3 = f2bf(v3);
            unsigned short l2 = f2bf(v2 - bf2f(h2)), l3 = f2bf(v3 - bf2f(h3));
            *(unsigned int*)&sAh[1][aoff] = (unsigned)h2 | ((unsigned)h3 << 16);
            *(unsigned int*)&sAl[1][aoff] = (unsigned)l2 | ((unsigned)l3 << 16);
        }
        __syncthreads();
        // ---- 2 k-chunks x 6 MFMA ----
        #pragma unroll
        for (int ks = 0; ks < 2; ++ks) {
            bf16x8 ah, al, bh[2], bl[2];
            {
                int p = (q + (fr >> 3)) & 3;
                int off = fr * 40 + p * 8;
                ah = *(const bf16x8*)&sAh[ks][off];
                al = *(const bf16x8*)&sAl[ks][off];
            }
            #pragma unroll
            for (int nt = 0; nt < 2; ++nt) {
                int off = q * 1032 + (wn + nt * 16 + fr) * 8;
                bh[nt] = *(const bf16x8*)&sBh[ks][off];
                bl[nt] = *(const bf16x8*)&sBl[ks][off];
            }
            #pragma unroll
            for (int nt = 0; nt < 2; ++nt) {
                acc[nt] = __builtin_amdgcn_mfma_f32_16x16x32_bf16(ah, bh[nt], acc[nt], 0, 0, 0);
                acc[nt] = __builtin_amdgcn_mfma_f32_16x16x32_bf16(ah, bl[nt], acc[nt], 0, 0, 0);
                acc[nt] = __builtin_amdgcn_mfma_f32_16x16x32_bf16(al, bh[nt], acc[nt], 0, 0, 0);
            }
        }
        __syncthreads();
    }
    // ---- epilogue phase 1: dump raw QTX into Gs (C/D: col=fr, row=q*4+r) ----
    #pragma unroll
    for (int nt = 0; nt < 2; ++nt) {
        int col = wn + nt * 16 + fr;
        #pragma unroll
        for (int r = 0; r < 4; ++r)
            Gs[q * 4 + r][col] = acc[nt][r];
    }
    __syncthreads();
    // ---- phase 2: Gs *= w(ev,col); par from global (L2-hot 24 KB) ----
    {
        int col = t & 127, rowg = t >> 7;    // 8 rows each
        float arr[S_], aii[S_], ccc[S_];
        #pragma unroll
        for (int ss = 0; ss < S_; ++ss) {
            arr[ss] = par[ss * D_ + col];
            aii[ss] = par[DS_ + ss * D_ + col];
            ccc[ss] = par[2 * DS_ + ss * D_ + col];
        }
        #pragma unroll
        for (int i = 0; i < 8; ++i) {
            int row = rowg * 8 + i;
            float ev = evS[row];
            float w = 0.f;
            #pragma unroll
            for (int ss = 0; ss < S_; ++ss) {
                float a = ev * arr[ss], bi = ev * aii[ss];
                float oma = 1.0f - a;            // exact (Sterbenz), a in [0.5,1]
                float b2 = bi * bi;
                float num = fmaf(a, oma, -b2);
                float den = fmaf(oma, oma, b2);  // no cancellation
                float rr = __builtin_amdgcn_rcpf(den);
                rr = rr * (2.0f - den * rr);
                w = fmaf(ccc[ss], num * rr, w);
            }
            Gs[row][col] *= w;
        }
    }
    __syncthreads();
    // ---- phase 3: swizzled bf16 hi/lo write-out (16 rows = half a ct) ----
    {
        int d = t & 127, kg = t >> 7;        // kg in {0,1}: rows kg*8..+8
        bf16x8 hv, lv;
        #pragma unroll
        for (int i = 0; i < 8; ++i) {
            float v = Gs[kg * 8 + i][d];
            unsigned short h = f2bf(v);
            hv[i] = (short)h;
            lv[i] = (short)f2bf(v - bf2f(h));
        }
        int ct = m0 >> 5;
        int qsel = ((m0 >> 3) & 2) + kg;     // quarter within the ct
        size_t off = (((size_t)(b * 32 + ct) * 4 + qsel) * 128 + d) * 8;
        *(bf16x8*)&GswH[off] = hv;
        *(bf16x8*)&GswL[off] = lv;
    }
}

// ---------------------------------------------------------------------------
// k_g2: GEMM2 (yssm = E @ G, tile 16l x 128d, BK=64) + rn/silu/out-proj
// epilogue -> writes y. Grid = 512 blocks -> 2 blocks/CU.
// ---------------------------------------------------------------------------
__global__ __launch_bounds__(256) void k_g2(
    const float* __restrict__ E,
    const unsigned short* __restrict__ BH, const unsigned short* __restrict__ BL,
    const float* __restrict__ rn, const float* __restrict__ W_out,
    const float* __restrict__ b_out, float* __restrict__ y) {
    __shared__ unsigned short sAh[2][640], sAl[2][640];
    __shared__ unsigned short sBh[2][4128], sBl[2][4128];
    __shared__ float Ys[16][132];
    __shared__ float rnS[16];
    int bx = blockIdx.x;
    int b = bx & 7;
    int m0 = (bx >> 3) * 16;                 // l-tile base
    const float* Ab = E + (size_t)b * (1024 * 1024);
    const unsigned short* BbH = BH + (size_t)b * 131072;
    const unsigned short* BbL = BL + (size_t)b * 131072;
    int t = threadIdx.x;
    int wave = t >> 6, lane = t & 63;
    int fr = lane & 15, q = lane >> 4;
    int wn = wave * 32;
    // A staging: thread t loads E[m0+am][cb + 4*(t&15) .. +4] (float4, row-major)
    int am = t >> 4, c4 = (t & 15) * 4;      // c4 in [0,64)
    int chunk = c4 >> 5, cw = c4 & 31;       // within-chunk offset {0,4,...,28}
    int ag = cw >> 3;
    int arot = (ag + (am >> 3)) & 3;
    int aoff = am * 40 + arot * 8 + (cw & 7);
    if (t < 16) rnS[t] = rn[b * 1024 + m0 + t];
    f32x4 acc[2];
    acc[0] = (f32x4){0.f, 0.f, 0.f, 0.f};
    acc[1] = (f32x4){0.f, 0.f, 0.f, 0.f};

    for (int it = 0; it < NIT_; ++it) {
        int cb = it * 64;
        // ---- A load: float4 (coalesced 256B over c4) ----
        float4 va = *(const float4*)&Ab[(size_t)(m0 + am) * 1024 + cb + c4];
        // ---- B glds: 2 ct-sections, 8 per wave ----
        #pragma unroll
        for (int j2 = 0; j2 < 8; ++j2) {
            int s = wave + j2 * 4;
            int cts = s >> 4, s2 = s & 15;
            int qq = s2 & 3, nh = (s2 >> 2) & 1, hl = s2 >> 3;
            size_t src0 = (size_t)(it * 2 + cts) * 4096;
            const unsigned short* src =
                (hl ? BbL : BbH) + src0 + ((size_t)qq * 128 + nh * 64 + lane) * 8;
            unsigned short* dst = (hl ? sBl[cts] : sBh[cts]) + qq * 1032 + nh * 512;
            __builtin_amdgcn_global_load_lds((gu32*)src, (lu32*)dst, 16, 0, 0);
        }
        // ---- convert + ds_write A (uint2 into selected chunk) ----
        {
            unsigned short h0 = f2bf(va.x), h1 = f2bf(va.y);
            unsigned short h2 = f2bf(va.z), h3 = f2bf(va.w);
            unsigned short l0 = f2bf(va.x - bf2f(h0)), l1 = f2bf(va.y - bf2f(h1));
            unsigned short l2 = f2bf(va.z - bf2f(h2)), l3 = f2bf(va.w - bf2f(h3));
            *(uint2*)&sAh[chunk][aoff] =
                (uint2){(unsigned)h0 | ((unsigned)h1 << 16),
                        (unsigned)h2 | ((unsigned)h3 << 16)};
            *(uint2*)&sAl[chunk][aoff] =
                (uint2){(unsigned)l0 | ((unsigned)l1 << 16),
                        (unsigned)l2 | ((unsigned)l3 << 16)};
        }
        __syncthreads();
        // ---- 2 k-chunks x 6 MFMA ----
        #pragma unroll
        for (int ks = 0; ks < 2; ++ks) {
            bf16x8 ah, al, bh[2], bl[2];
            {
                int p = (q + (fr >> 3)) & 3;
                int off = fr * 40 + p * 8;
                ah = *(const bf16x8*)&sAh[ks][off];
                al = *(const bf16x8*)&sAl[ks][off];
            }
            #pragma unroll
            for (int nt = 0; nt < 2; ++nt) {
                int off = q * 1032 + (wn + nt * 16 + fr) * 8;
                bh[nt] = *(const bf16x8*)&sBh[ks][off];
                bl[nt] = *(const bf16x8*)&sBl[ks][off];
            }
            #pragma unroll
            for (int nt = 0; nt < 2; ++nt) {
                acc[nt] = __builtin_amdgcn_mfma_f32_16x16x32_bf16(ah, bh[nt], acc[nt], 0, 0, 0);
                acc[nt] = __builtin_amdgcn_mfma_f32_16x16x32_bf16(ah, bl[nt], acc[nt], 0, 0, 0);
                acc[nt] = __builtin_amdgcn_mfma_f32_16x16x32_bf16(al, bh[nt], acc[nt], 0, 0, 0);
            }
        }
        __syncthreads();
    }
    // ---- fused epilogue: Ys = silu(yssm*rn) ----
    #pragma unroll
    for (int nt = 0; nt < 2; ++nt) {
        int col = wn + nt * 16 + fr;
        #pragma unroll
        for (int r = 0; r < 4; ++r) {
            int row = q * 4 + r;
            float v = acc[nt][r] * rnS[row];
            float sig = 1.0f / (1.0f + __expf(-v));
            Ys[row][col] = v * sig;
        }
    }
    __syncthreads();
    // ---- out-proj: y = Ys @ W_out + b_out ----
    int j = t & 127, h = t >> 7;             // h in {0,1}: 8 rows each
    float a2[8];
    #pragma unroll
    for (int r = 0; r < 8; ++r) a2[r] = 0.f;
    for (int dd = 0; dd < 128; dd += 4) {
        float w0 = W_out[(dd + 0) * 128 + j];
        float w1 = W_out[(dd + 1) * 128 + j];
        float w2 = W_out[(dd + 2) * 128 + j];
        float w3 = W_out[(dd + 3) * 128 + j];
        #pragma unroll
        for (int r = 0; r < 8; ++r) {
            float4 yv = *(float4*)&Ys[h * 8 + r][dd];
            a2[r] = fmaf(yv.x, w0, a2[r]);
            a2[r] = fmaf(yv.y, w1, a2[r]);
            a2[r] = fmaf(yv.z, w2, a2[r]);
            a2[r] = fmaf(yv.w, w3, a2[r]);
        }
    }
    float bo = b_out[j];
    #pragma unroll
    for (int r = 0; r < 8; ++r)
        y[((size_t)b * 1024 + m0 + h * 8 + r) * 128 + j] = a2[r] + bo;
}

// ---------------------------------------------------------------------------
extern "C" void kernel_launch(void* const* d_in, const int* in_sizes, int n_in,
                              void* d_out, int out_size, void* d_ws, size_t ws_size,
                              hipStream_t stream) {
    const float* x          = (const float*)d_in[0];
    const float* EigVecs    = (const float*)d_in[2];
    const float* EigVals    = (const float*)d_in[3];
    const float* bn_gamma   = (const float*)d_in[4];
    const float* bn_beta    = (const float*)d_in[5];
    const float* bn_mean    = (const float*)d_in[6];
    const float* bn_var     = (const float*)d_in[7];
    const float* W_in       = (const float*)d_in[8];
    const float* b_in       = (const float*)d_in[9];
    const float* log_Delta  = (const float*)d_in[10];
    const float* Bp         = (const float*)d_in[11];
    const float* Cp         = (const float*)d_in[12];
    const float* log_A_real = (const float*)d_in[13];
    const float* A_imag     = (const float*)d_in[14];
    const float* W_out      = (const float*)d_in[15];
    const float* b_out      = (const float*)d_in[16];

    float* y = (float*)d_out;
    char* w = (char*)d_ws;
    float* rn            = (float*)(w);                       // 32 KB
    float* par           = (float*)(w + 32768);               // 24 KB
    unsigned short* uswH = (unsigned short*)(w + 65536);      // 2 MB each
    unsigned short* uswL = (unsigned short*)(w + 65536 + (1u << 21));
    unsigned short* GswH = (unsigned short*)(w + 65536 + 2 * (1u << 21));
    unsigned short* GswL = (unsigned short*)(w + 65536 + 3 * (1u << 21));

    k_pre<<<dim3(B_ * L_ / 16), dim3(256), 0, stream>>>(
        EigVecs, x, bn_gamma, bn_beta, bn_mean, bn_var, W_in, b_in,
        log_Delta, Bp, Cp, log_A_real, A_imag, rn, par, uswH, uswL);
    k_g1<<<dim3(512), dim3(256), 0, stream>>>(
        EigVecs, uswH, uswL, EigVals, par, GswH, GswL);
    k_g2<<<dim3(512), dim3(256), 0, stream>>>(
        EigVecs, GswH, GswL, rn, W_out, b_out, y);
}